// Round 5
// baseline (575.872 us; speedup 1.0000x reference)
//
#include <hip/hip_runtime.h>
#include <hip/hip_bf16.h>
#include <math.h>

// Problem constants
#define B_   512
#define NS_  2
#define S_   128
#define H_   768
#define DS_  384
#define NL_  40
#define H3_  (3*H_)      // 2304
#define TEMP_ 0.05f
#define ALPHA_ 0.15f
#define GAMMA_ 7.5f
#define EPS_ 1e-8f

typedef __attribute__((ext_vector_type(8))) short bf8_t;
typedef __attribute__((ext_vector_type(4))) float f4_t;

#define LDSPAD 40   // bf16 row stride for 32-wide k tiles (80B, 16B-aligned)

// ---------------- helpers ----------------

__device__ __forceinline__ float block_reduce_sum(float v, float* sh) {
    int t = threadIdx.x;
    sh[t] = v; __syncthreads();
    for (int s = blockDim.x / 2; s > 0; s >>= 1) {
        if (t < s) sh[t] += sh[t + s];
        __syncthreads();
    }
    float r = sh[0]; __syncthreads();
    return r;
}

__device__ __forceinline__ float block_reduce_max(float v, float* sh) {
    int t = threadIdx.x;
    sh[t] = v; __syncthreads();
    for (int s = blockDim.x / 2; s > 0; s >>= 1) {
        if (t < s) sh[t] = fmaxf(sh[t], sh[t + s]);
        __syncthreads();
    }
    float r = sh[0]; __syncthreads();
    return r;
}

// reduce v across the 16 contiguous lanes of this quad-group; result valid at lr==0
__device__ __forceinline__ float quadgroup_reduce(float v) {
    v += __shfl_down(v, 8);
    v += __shfl_down(v, 4);
    v += __shfl_down(v, 2);
    v += __shfl_down(v, 1);
    return v;
}

__device__ __forceinline__ float inv_norm(float ssq) {
    return 1.0f / fmaxf(sqrtf(ssq), EPS_);
}

// ---------------- kernel 1: prep ----------------
// blocks [0,512): gather batch b (block 0 also zeroes acc/done/ssq)
// blocks [512,1088):  transpose dense_w (768x768)  -> dwt (768x768)
// blocks [1088,1952): transpose fc_w   (2304x384)  -> fwt (384x2304)
// blocks [1952,2096): transpose cls_w  (2304x40)   -> cwt (48x2304, rows 40..47 zeroed)
// blocks [2096,2608): desc row L2-norm -> desc_nb (fp32 norm, bf16 out)
__device__ __forceinline__ void transpose_tile(
    const float* __restrict__ in, __hip_bfloat16* __restrict__ out,
    int K, int N, int kt, int nt, int tid, float* tileLds /* 32*33 */)
{
    int k0 = kt * 32, n0 = nt * 32;
    int tx = tid & 31, ty = tid >> 5;   // ty 0..7
#pragma unroll
    for (int i = 0; i < 4; ++i) {
        int k = k0 + ty + i * 8, n = n0 + tx;
        if (k < K && n < N) tileLds[(ty + i*8) * 33 + tx] = in[(size_t)k * N + n];
    }
    __syncthreads();
#pragma unroll
    for (int i = 0; i < 4; ++i) {
        int n = n0 + ty + i * 8, k = k0 + tx;
        if (n < N && k < K) out[(size_t)n * K + k] = __float2bfloat16(tileLds[tx * 33 + ty + i*8]);
    }
}

__global__ __launch_bounds__(256) void prep_kernel(
    const float* __restrict__ bert, const int* __restrict__ eidx,
    const float* __restrict__ dense_w, const float* __restrict__ fc_w,
    const float* __restrict__ cls_w, const float* __restrict__ desc,
    __hip_bfloat16* __restrict__ rh_bf, __hip_bfloat16* __restrict__ toks_bf,
    __hip_bfloat16* __restrict__ dwt, __hip_bfloat16* __restrict__ fwt,
    __hip_bfloat16* __restrict__ cwt, __hip_bfloat16* __restrict__ desc_nb,
    float* __restrict__ relssq, float* __restrict__ zssq,
    float* __restrict__ acc, int* __restrict__ done)
{
    __shared__ float tileLds[32 * 33];
    int blk = blockIdx.x;
    int t = threadIdx.x;
    if (blk < 512) {
        int b = blk;
        if (b == 0) {
            for (int i = t; i < 512; i += 256) relssq[i] = 0.0f;
            for (int i = t; i < 1024; i += 256) zssq[i] = 0.0f;
            if (t < 4) acc[t] = 0.0f;
            if (t == 4) *done = 0;
        }
        int e00 = eidx[b*4 + 0];
        int e01 = eidx[b*4 + 1];
        int e10 = eidx[b*4 + 2];
        int e11 = eidx[b*4 + 3];
        const float* s0 = bert + (size_t)b * NS_ * S_ * H_;
        const float* s1 = s0 + (size_t)S_ * H_;
        const float* cls  = s0;
        const float* head = s0 + (size_t)e00 * H_;
        const float* tail = s0 + (size_t)e01 * H_;
        const float* h2a  = s1 + (size_t)e10 * H_;
        const float* h2b  = s1 + (size_t)e11 * H_;
        __hip_bfloat16* rhb = rh_bf + (size_t)b * H3_;
        __hip_bfloat16* tk  = toks_bf + (size_t)b * 4 * H_;
        for (int h = t; h < H_; h += 256) {
            float c  = cls[h];
            float hd = head[h];
            float tl = tail[h];
            rhb[h]        = __float2bfloat16(tanhf(c));
            rhb[H_ + h]   = __float2bfloat16(tanhf(hd));
            rhb[2*H_ + h] = __float2bfloat16(tanhf(tl));
            tk[h]         = __float2bfloat16(hd);
            tk[H_ + h]    = __float2bfloat16(tl);
            tk[2*H_ + h]  = __float2bfloat16(h2a[h]);
            tk[3*H_ + h]  = __float2bfloat16(h2b[h]);
        }
    } else if (blk < 1088) {
        int q = blk - 512;          // 24x24 tiles
        transpose_tile(dense_w, dwt, H_, H_, q / 24, q % 24, t, tileLds);
    } else if (blk < 1952) {
        int q = blk - 1088;         // 72x12 tiles
        transpose_tile(fc_w, fwt, H3_, DS_, q / 12, q % 12, t, tileLds);
    } else if (blk < 2096) {
        int q = blk - 1952;         // 72x2 tiles
        int kt = q / 2, nt = q % 2;
        transpose_tile(cls_w, cwt, H3_, NL_, kt, nt, t, tileLds);
        if (nt == 1) {              // zero pad rows 40..47 for this k-range
            int tx = t & 31, ty = t >> 5;
            cwt[(size_t)(40 + ty) * H3_ + kt * 32 + tx] = __float2bfloat16(0.0f);
        }
    } else {
        int i = blk - 2096;         // desc norm, D=384
        const float* x = desc + (size_t)i * DS_;
        float ss = 0.0f;
        for (int d = t; d < DS_; d += 256) { float v = x[d]; ss += v * v; }
        ss = block_reduce_sum(ss, tileLds);
        float inv = inv_norm(ss);
        __hip_bfloat16* o = desc_nb + (size_t)i * DS_;
        for (int d = t; d < DS_; d += 256) o[d] = __float2bfloat16(x[d] * inv);
    }
}

// ---------------- dense 128x128 body: toks_z = bf16(tanh(A@W^T + b)), ssq -> zssq ----------------
__device__ __forceinline__ void dense_body(
    const __hip_bfloat16* __restrict__ A, const __hip_bfloat16* __restrict__ Bp,
    const float* __restrict__ bias, __hip_bfloat16* __restrict__ toks_z,
    float* __restrict__ zssq, int bx, int by,
    __hip_bfloat16* As, __hip_bfloat16* Bs)
{
    int tid  = threadIdx.x;
    int lane = tid & 63;
    int wave = tid >> 6;
    int wm = (wave >> 1) * 64;
    int wn = (wave & 1) * 64;
    int lr = lane & 15;
    int quad = lane >> 4;
    int rowBase = by * 128;
    int colBase = bx * 128;

    f4_t acc[4][4];
#pragma unroll
    for (int i = 0; i < 4; ++i)
#pragma unroll
        for (int j = 0; j < 4; ++j) acc[i][j] = (f4_t){0.f, 0.f, 0.f, 0.f};

    int sr = tid >> 2, sc = tid & 3;
    for (int k0 = 0; k0 < H_; k0 += 32) {
#pragma unroll
        for (int half = 0; half < 2; ++half) {
            int r = sr + half * 64;
            *(bf8_t*)&As[r * LDSPAD + sc * 8] =
                *(const bf8_t*)(A + (size_t)(rowBase + r) * H_ + k0 + sc * 8);
            *(bf8_t*)&Bs[r * LDSPAD + sc * 8] =
                *(const bf8_t*)(Bp + (size_t)(colBase + r) * H_ + k0 + sc * 8);
        }
        __syncthreads();
        bf8_t af[4], bfr[4];
#pragma unroll
        for (int f = 0; f < 4; ++f) {
            af[f]  = *(const bf8_t*)&As[(wm + f*16 + lr) * LDSPAD + quad * 8];
            bfr[f] = *(const bf8_t*)&Bs[(wn + f*16 + lr) * LDSPAD + quad * 8];
        }
#pragma unroll
        for (int i = 0; i < 4; ++i)
#pragma unroll
            for (int j = 0; j < 4; ++j)
                acc[i][j] = __builtin_amdgcn_mfma_f32_16x16x32_bf16(af[i], bfr[j], acc[i][j], 0, 0, 0);
        __syncthreads();
    }
    // epilogue: v = tanh(acc + bias); write bf16; row-ssq -> zssq (atomic)
    float bv[4];
#pragma unroll
    for (int j = 0; j < 4; ++j) bv[j] = bias[colBase + wn + j*16 + lr];
#pragma unroll
    for (int i = 0; i < 4; ++i) {
#pragma unroll
        for (int r = 0; r < 4; ++r) {
            int row = rowBase + wm + i*16 + quad*4 + r;
            float s = 0.0f;
#pragma unroll
            for (int j = 0; j < 4; ++j) {
                float v = tanhf(acc[i][j][r] + bv[j]);
                toks_z[(size_t)row * H_ + colBase + wn + j*16 + lr] = __float2bfloat16(v);
                s += v * v;
            }
            s = quadgroup_reduce(s);
            if (lr == 0) {
                int zrow = (row >> 2) * 2 + ((row & 3) >> 1);
                atomicAdd(&zssq[zrow], s);
            }
        }
    }
}

// ---------------- fc 64x64 body: rel_bf = bf16(A@W^T + b), ssq -> relssq ----------------
__device__ __forceinline__ void fc_body(
    const __hip_bfloat16* __restrict__ A, const __hip_bfloat16* __restrict__ Bp,
    const float* __restrict__ bias, __hip_bfloat16* __restrict__ rel_bf,
    float* __restrict__ relssq, int bx, int by,
    __hip_bfloat16* As, __hip_bfloat16* Bs)
{
    int tid  = threadIdx.x;
    int lane = tid & 63;
    int wave = tid >> 6;
    int lr = lane & 15;
    int quad = lane >> 4;
    int rowBase = by * 64;
    int colBase = bx * 64;

    f4_t acc[4];
#pragma unroll
    for (int i = 0; i < 4; ++i) acc[i] = (f4_t){0.f, 0.f, 0.f, 0.f};

    int sr = tid >> 2, sc = tid & 3;
    for (int k0 = 0; k0 < H3_; k0 += 32) {
        *(bf8_t*)&As[sr * LDSPAD + sc * 8] =
            *(const bf8_t*)(A + (size_t)(rowBase + sr) * H3_ + k0 + sc * 8);
        *(bf8_t*)&Bs[sr * LDSPAD + sc * 8] =
            *(const bf8_t*)(Bp + (size_t)(colBase + sr) * H3_ + k0 + sc * 8);
        __syncthreads();
        bf8_t bfr = *(const bf8_t*)&Bs[(wave*16 + lr) * LDSPAD + quad * 8];
#pragma unroll
        for (int f = 0; f < 4; ++f) {
            bf8_t af = *(const bf8_t*)&As[(f*16 + lr) * LDSPAD + quad * 8];
            acc[f] = __builtin_amdgcn_mfma_f32_16x16x32_bf16(af, bfr, acc[f], 0, 0, 0);
        }
        __syncthreads();
    }
    int col = colBase + wave*16 + lr;
    float bv = bias[col];
#pragma unroll
    for (int f = 0; f < 4; ++f) {
#pragma unroll
        for (int r = 0; r < 4; ++r) {
            int row = rowBase + f*16 + quad*4 + r;
            float v = acc[f][r] + bv;
            rel_bf[(size_t)row * DS_ + col] = __float2bfloat16(v);
            float s = quadgroup_reduce(v * v);
            if (lr == 0) atomicAdd(&relssq[row], s);
        }
    }
}

// ---------------- cls logits + CE, 16 rows/block, K split across 4 waves ----------------
__device__ __forceinline__ void cls_ce_body(
    const __hip_bfloat16* __restrict__ rh, const __hip_bfloat16* __restrict__ cwt,
    const float* __restrict__ cls_b, const int* __restrict__ labels,
    float* __restrict__ acc, int rowBase, float* lgp /* 4*16*48 floats */)
{
    int tid  = threadIdx.x;
    int lane = tid & 63;
    int wave = tid >> 6;
    int lr = lane & 15;
    int quad = lane >> 4;

    f4_t a3[3];
#pragma unroll
    for (int j = 0; j < 3; ++j) a3[j] = (f4_t){0.f, 0.f, 0.f, 0.f};

    int kw0 = wave * (H3_ / 4);    // 576 per wave
    const __hip_bfloat16* aRow = rh + (size_t)(rowBase + lr) * H3_ + quad * 8;
#pragma unroll 2
    for (int s = 0; s < 18; ++s) {
        int k = kw0 + s * 32;
        bf8_t af = *(const bf8_t*)(aRow + k);
#pragma unroll
        for (int j = 0; j < 3; ++j) {
            bf8_t bfr = *(const bf8_t*)(cwt + (size_t)(j*16 + lr) * H3_ + k + quad * 8);
            a3[j] = __builtin_amdgcn_mfma_f32_16x16x32_bf16(af, bfr, a3[j], 0, 0, 0);
        }
    }
#pragma unroll
    for (int j = 0; j < 3; ++j) {
        int col = j*16 + lr;
#pragma unroll
        for (int r = 0; r < 4; ++r)
            lgp[wave * 768 + (quad*4 + r) * 48 + col] = a3[j][r];
    }
    __syncthreads();
    for (int idx = tid; idx < 768; idx += 256) {
        int col = idx % 48;
        float s = lgp[idx] + lgp[768 + idx] + lgp[1536 + idx] + lgp[2304 + idx];
        s = (col < NL_) ? (s + cls_b[col]) : -INFINITY;
        lgp[idx] = s;
    }
    __syncthreads();
    if (tid < 64) {
        float ce = 0.0f;
        if (tid < 16) {
            const float* Lr = &lgp[tid * 48];
            float m = -INFINITY;
            for (int c = 0; c < NL_; ++c) m = fmaxf(m, Lr[c]);
            float s = 0.0f;
            for (int c = 0; c < NL_; ++c) s += expf(Lr[c] - m);
            ce = logf(s) + m - Lr[labels[rowBase + tid]];
        }
        for (int off = 8; off >= 1; off >>= 1) ce += __shfl_down(ce, off);
        if (tid == 0) atomicAdd(acc + 0, ce * (1.0f / (float)B_));
    }
}

// ---------------- kernel 2: dense(96) + fc(48) + cls_ce(32) ----------------
__global__ __launch_bounds__(256) void gemms_kernel(
    const __hip_bfloat16* __restrict__ toks_bf, const __hip_bfloat16* __restrict__ dwt,
    const float* __restrict__ dense_b, __hip_bfloat16* __restrict__ toks_z,
    const __hip_bfloat16* __restrict__ rh_bf, const __hip_bfloat16* __restrict__ fwt,
    const float* __restrict__ fc_b, __hip_bfloat16* __restrict__ rel_bf,
    const __hip_bfloat16* __restrict__ cwt, const float* __restrict__ cls_b,
    const int* __restrict__ labels, float* __restrict__ relssq,
    float* __restrict__ zssq, float* __restrict__ acc)
{
    __shared__ __align__(16) char smem[2 * 128 * LDSPAD * 2];   // 20480 B
    int blk = blockIdx.x;
    if (blk < 96) {
        dense_body(toks_bf, dwt, dense_b, toks_z, zssq, blk % 6, blk / 6,
                   (__hip_bfloat16*)smem, (__hip_bfloat16*)(smem + 128 * LDSPAD * 2));
    } else if (blk < 144) {
        int q = blk - 96;
        fc_body(rh_bf, fwt, fc_b, rel_bf, relssq, q % 6, q / 6,
                (__hip_bfloat16*)smem, (__hip_bfloat16*)(smem + 64 * LDSPAD * 2));
    } else {
        cls_ce_body(rh_bf, cwt, cls_b, labels, acc, (blk - 144) * 16, (float*)smem);
    }
}

// ---------------- kernel 3: C1 (64) + C2 (64), norm-scaled epilogues ----------------
// C1[i][j] = (rel_bf[i] . desc_nb[j]) * inv_rel[i]          (desc pre-normalized)
// C2[i][j] = (z1[i] . z2[j]) * inv_z1[i] * inv_z2[j] / TEMP
__device__ __forceinline__ void sim_body(
    const __hip_bfloat16* __restrict__ A, const __hip_bfloat16* __restrict__ Bp,
    float* __restrict__ C, int K, int lda, int ldb,
    const float* __restrict__ rssq, const float* __restrict__ cssq,
    int rstride, int roff, int cstride, int coff, float scale,
    int bx, int by, __hip_bfloat16* As, __hip_bfloat16* Bs)
{
    int tid  = threadIdx.x;
    int lane = tid & 63;
    int wave = tid >> 6;
    int lr = lane & 15;
    int quad = lane >> 4;
    int rowBase = by * 64;
    int colBase = bx * 64;

    f4_t acc[4];
#pragma unroll
    for (int i = 0; i < 4; ++i) acc[i] = (f4_t){0.f, 0.f, 0.f, 0.f};

    int sr = tid >> 2, sc = tid & 3;
    for (int k0 = 0; k0 < K; k0 += 32) {
        *(bf8_t*)&As[sr * LDSPAD + sc * 8] =
            *(const bf8_t*)(A + (size_t)(rowBase + sr) * lda + k0 + sc * 8);
        *(bf8_t*)&Bs[sr * LDSPAD + sc * 8] =
            *(const bf8_t*)(Bp + (size_t)(colBase + sr) * ldb + k0 + sc * 8);
        __syncthreads();
        bf8_t bfr = *(const bf8_t*)&Bs[(wave*16 + lr) * LDSPAD + quad * 8];
#pragma unroll
        for (int f = 0; f < 4; ++f) {
            bf8_t af = *(const bf8_t*)&As[(f*16 + lr) * LDSPAD + quad * 8];
            acc[f] = __builtin_amdgcn_mfma_f32_16x16x32_bf16(af, bfr, acc[f], 0, 0, 0);
        }
        __syncthreads();
    }
    int col = colBase + wave*16 + lr;
    float cinv = cssq ? inv_norm(cssq[col * cstride + coff]) : 1.0f;
#pragma unroll
    for (int f = 0; f < 4; ++f) {
#pragma unroll
        for (int r = 0; r < 4; ++r) {
            int row = rowBase + f*16 + quad*4 + r;
            float rinv = inv_norm(rssq[row * rstride + roff]);
            C[(size_t)row * B_ + col] = acc[f][r] * rinv * cinv * scale;
        }
    }
}

__global__ __launch_bounds__(256) void c1c2_kernel(
    const __hip_bfloat16* __restrict__ rel_bf, const __hip_bfloat16* __restrict__ desc_nb,
    const __hip_bfloat16* __restrict__ toks_z,
    const float* __restrict__ relssq, const float* __restrict__ zssq,
    float* __restrict__ C1, float* __restrict__ C2)
{
    __shared__ __align__(16) char smem[2 * 64 * LDSPAD * 2];
    __hip_bfloat16* As = (__hip_bfloat16*)smem;
    __hip_bfloat16* Bs = (__hip_bfloat16*)(smem + 64 * LDSPAD * 2);
    int blk = blockIdx.x;
    if (blk < 64) {
        sim_body(rel_bf, desc_nb, C1, DS_, DS_, DS_,
                 relssq, (const float*)nullptr, 1, 0, 0, 0, 1.0f,
                 blk % 8, blk / 8, As, Bs);
    } else {
        int q = blk - 64;
        sim_body(toks_z, toks_z + 2*H_, C2, 2*H_, 4*H_, 4*H_,
                 zssq, zssq, 2, 0, 2, 1, 1.0f / TEMP_,
                 q % 8, q / 8, As, Bs);
    }
}

// ---------------- kernel 4: margin (512) + cos-CE (512) + last-block finalize ----------------
__global__ __launch_bounds__(256) void tail_kernel(
    const float* __restrict__ C1, const float* __restrict__ C2,
    const int* __restrict__ labels, float* __restrict__ acc,
    int* __restrict__ done, float* __restrict__ out)
{
    __shared__ float sh[256];
    int blk = blockIdx.x, t = threadIdx.x;
    if (blk < 512) {
        int i = blk;
        int li = labels[i];
        const float* row = C1 + (size_t)i * B_;
        float m = -INFINITY;
        for (int j = t; j < B_; j += 256)
            if (labels[j] != li) m = fmaxf(m, row[j]);
        float negmax = block_reduce_max(m, sh);
        if (t == 0) {
            float neg = fmaxf(negmax, 0.0f);
            float term = neg - row[i] + GAMMA_;
            if (term > 0.0f) atomicAdd(acc + 1, term);
        }
    } else {
        int i = blk - 512;
        const float* row = C2 + (size_t)i * B_;
        float m = -INFINITY;
        for (int j = t; j < B_; j += 256) m = fmaxf(m, row[j]);
        m = block_reduce_max(m, sh);
        float s = 0.0f;
        for (int j = t; j < B_; j += 256) s += expf(row[j] - m);
        s = block_reduce_sum(s, sh);
        if (t == 0) atomicAdd(acc + 2, (logf(s) + m - row[i]) * (1.0f / (float)B_));
    }
    __threadfence();
    if (t == 0) {
        int prev = atomicAdd(done, 1);
        if (prev == 1023) {
            float a0 = atomicAdd(acc + 0, 0.0f);
            float a1 = atomicAdd(acc + 1, 0.0f);
            float a2 = atomicAdd(acc + 2, 0.0f);
            out[0] = a0 + (1.0f - ALPHA_) * a1 + ALPHA_ * a2;
        }
    }
}

// ---------------- launch ----------------

extern "C" void kernel_launch(void* const* d_in, const int* in_sizes, int n_in,
                              void* d_out, int out_size, void* d_ws, size_t ws_size,
                              hipStream_t stream) {
    const float* bert     = (const float*)d_in[0];
    const float* desc     = (const float*)d_in[1];
    const float* dense_w  = (const float*)d_in[2];
    const float* dense_b  = (const float*)d_in[3];
    const float* cls_w    = (const float*)d_in[4];
    const float* cls_b    = (const float*)d_in[5];
    const float* fc_w     = (const float*)d_in[6];
    const float* fc_b     = (const float*)d_in[7];
    const int*   eidx     = (const int*)d_in[8];
    const int*   labels   = (const int*)d_in[9];
    float* out = (float*)d_out;

    float* fp = (float*)d_ws;
    __hip_bfloat16* rh_bf   = (__hip_bfloat16*)fp; fp += (size_t)B_*H3_/2;
    __hip_bfloat16* toks_bf = (__hip_bfloat16*)fp; fp += (size_t)B_*4*H_/2;
    __hip_bfloat16* dwt_bf  = (__hip_bfloat16*)fp; fp += (size_t)H_*H_/2;
    __hip_bfloat16* fwt_bf  = (__hip_bfloat16*)fp; fp += (size_t)DS_*H3_/2;
    __hip_bfloat16* cwt_bf  = (__hip_bfloat16*)fp; fp += (size_t)48*H3_/2;   // padded to 48 rows
    __hip_bfloat16* desc_nb = (__hip_bfloat16*)fp; fp += (size_t)B_*DS_/2;
    __hip_bfloat16* toks_z  = (__hip_bfloat16*)fp; fp += (size_t)B_*4*H_/2;  // tanh'd dense out
    __hip_bfloat16* rel_bf  = (__hip_bfloat16*)fp; fp += (size_t)B_*DS_/2;   // fc out (un-normalized)
    float* C1       = fp; fp += (size_t)B_*B_;
    float* C2       = fp; fp += (size_t)B_*B_;
    float* relssq   = fp; fp += 512;
    float* zssq     = fp; fp += 1024;   // [2b]=||z1_b||^2, [2b+1]=||z2_b||^2
    float* acc      = fp; fp += 4;
    int*   done     = (int*)fp;

    // 1. prep: gather + transposes + desc norm (+ zero ssq/acc/done)
    prep_kernel<<<2608, 256, 0, stream>>>(bert, eidx, dense_w, fc_w, cls_w, desc,
                                          rh_bf, toks_bf, dwt_bf, fwt_bf, cwt_bf,
                                          desc_nb, relssq, zssq, acc, done);

    // 2. dense + fc + cls_ce; epilogues write bf16 + row sum-of-squares
    gemms_kernel<<<176, 256, 0, stream>>>(toks_bf, dwt_bf, dense_b, toks_z,
                                          rh_bf, fwt_bf, fc_b, rel_bf,
                                          cwt_bf, cls_b, labels, relssq, zssq, acc);

    // 3. C1 + C2 with norm scaling in epilogue
    c1c2_kernel<<<128, 256, 0, stream>>>(rel_bf, desc_nb, toks_z, relssq, zssq, C1, C2);

    // 4. margin + cos-CE + finalize
    tail_kernel<<<1024, 256, 0, stream>>>(C1, C2, labels, acc, done, out);
}